// Round 4
// baseline (43098.923 us; speedup 1.0000x reference)
//
#include <hip/hip_runtime.h>
#include <math.h>

// Problem constants: B=32, T=1024, C=1024
#define CC    1024
#define CC2   2048
#define BB    32
#define TT    1024
#define NBLK  256      // persistent grid: 1 block/CU, all co-resident
#define NTHR  512      // 8 waves/block
#define LNEPS 1e-5f

// Workspace layout (float indices)
#define WS_Y    32768    // y:  32*2048 (coherent: sc-bypass stores/loads only)
#define WS_Y2   98304    // y2: 32*1024 (coherent)
#define WS_BARF 131072   // barrier: cnt[64] arrival counters (monotonic)

// LDS layout (float offsets). Two 16448-float pipeline buffers, each split
// into an activation region (z for A / y for B) and a weight region (Wa/Wb).
#define RB0   0
#define RB1   16448
#define RWOFF 8224
#define SC0F  32896      // reduce scratch (2304 floats)
#define GB_G  35200      // gamma[1024]
#define GB_B  36224      // beta[1024]
#define SMEMN 37248      // 148,992 B (< 160 KiB/CU)

// CPol aux bits (gfx950): bit0=SC0, bit4=SC1. SC0|SC1 = system coherent point.
#define AUX_CACHED 0
#define AUX_COH    17

typedef float    nfloat4 __attribute__((ext_vector_type(4)));
typedef unsigned nuint4  __attribute__((ext_vector_type(4)));

// Counted waits + raw barriers: avoids __syncthreads()'s vmcnt(0) drain so
// prefetched global_load_lds stay in flight across barriers (T3/T4 pattern).
#define WAIT_VM(N)  do { asm volatile("s_waitcnt vmcnt(" #N ")" ::: "memory"); \
                         __builtin_amdgcn_sched_barrier(0); } while (0)
#define WAIT_LGKM0  do { asm volatile("s_waitcnt lgkmcnt(0)" ::: "memory"); \
                         __builtin_amdgcn_sched_barrier(0); } while (0)
#define SBAR()      do { __builtin_amdgcn_s_barrier(); \
                         __builtin_amdgcn_sched_barrier(0); } while (0)

__global__ void rpe_init(float* __restrict__ ws) {
    unsigned* bar = (unsigned*)(ws + WS_BARF);
    const int i = blockIdx.x * blockDim.x + threadIdx.x;
    if (i < 128) bar[i] = 0u;   // cnt[64] + pad; ws poisoned 0xAA between runs
}

// ---- coherent primitives --------------------------------------------------
__device__ __forceinline__ unsigned spin_load_u32(const unsigned* p) {
    unsigned v;
    asm volatile("global_load_dword %0, %1, off sc0 sc1\n\ts_waitcnt vmcnt(0)"
                 : "=&v"(v) : "v"(p) : "memory");
    return v;
}
__device__ __forceinline__ nfloat4 coh_load_f32x4_nowait(const float* p) {
    nfloat4 v;
    asm volatile("global_load_dwordx4 %0, %1, off sc0 sc1"
                 : "=&v"(v) : "v"(p));
    return v;
}
__device__ __forceinline__ void async_cp16(const float* g, float* l) {
    __builtin_amdgcn_global_load_lds(
        (const __attribute__((address_space(1))) void*)g,
        (__attribute__((address_space(3))) void*)l, 16, 0, AUX_CACHED);
}
__device__ __forceinline__ void async_cp16_coh(const float* g, float* l) {
    __builtin_amdgcn_global_load_lds(
        (const __attribute__((address_space(1))) void*)g,
        (__attribute__((address_space(3))) void*)l, 16, 0, AUX_COH);
}
__device__ __forceinline__ void coh_store(float* p, float v) {
    __hip_atomic_store(p, v, __ATOMIC_RELAXED, __HIP_MEMORY_SCOPE_AGENT);
}
__device__ __forceinline__ float gelu_exact(float a) {
    return 0.5f * a * (1.0f + erff(a * 0.70710678118654752440f));
}

// ---- grid barrier: 64-counter arrive, all-blocks wave-0 poll, no release --
// Steady state is RMW-FREE: arrivals are 4-way atomicAdds on 64 distinct
// words; the spin is plain sc0|sc1 dword loads (served at the LLC coherent
// point; proven coherent by the data path). Round-3's /8 RMW fallback put
// ~150-250 serialized RMWs on ONE line per barrier -> several us of LLC
// atomic-unit queueing; the valve is now /1024 (pure hang-safety, ~never).
__device__ __forceinline__ void bar_core(unsigned* cnt, unsigned phase,
                                         int blk, int tid) {
    if (tid == 0)
        __hip_atomic_fetch_add(&cnt[blk & 63], 1u,
                               __ATOMIC_RELAXED, __HIP_MEMORY_SCOPE_AGENT);
    if (tid < 64) {
        const unsigned target = 4u * phase;   // 4 blocks per counter word
        unsigned* w = cnt + tid;
        int n = 0;
        for (;;) {
            unsigned v = ((++n & 1023) == 0)
                ? __hip_atomic_fetch_add(w, 0u, __ATOMIC_RELAXED,
                                         __HIP_MEMORY_SCOPE_AGENT)
                : spin_load_u32(w);
            if (__ballot(v >= target) == ~0ull) break;
            __builtin_amdgcn_s_sleep(1);
        }
    }
    SBAR();   // raw barrier: do NOT drain vmcnt (prefetches stay in flight)
}

extern "C" __global__ void __launch_bounds__(NTHR)
rpe_main(const float* __restrict__ x,  const float* __restrict__ Wa,
         const float* __restrict__ ba, const float* __restrict__ Wb,
         const float* __restrict__ bbv, const float* __restrict__ gamma,
         const float* __restrict__ beta, float* __restrict__ out,
         float* __restrict__ ws)
{
    float*    y_ws  = ws + WS_Y;
    float*    y2_ws = ws + WS_Y2;
    unsigned* cnt   = (unsigned*)(ws + WS_BARF);

    const int tid  = threadIdx.x;
    const int blk  = blockIdx.x;
    const int wv   = tid >> 6;
    const int lane = tid & 63;
    const int pos  = lane & 7;
    const int ks   = lane >> 3;

    __shared__ float smem[SMEMN];

    // XCD-partner mapping (perf-only): blocks sharing a weight slice land on
    // the same XCD (blk%8 round-robin) -> per-XCD Wa 2MB + Wb 1MB < 4MB L2.
    const int xcd  = blk & 7;
    const int slot = blk >> 3;

    const int j0  = (xcd * 16 + (slot & 15)) * 16;   // Phase A: 16 j-grps/XCD x 2 b-halves
    const int b0A = (slot >> 4) * 16;
    const int i0  = (xcd * 8 + (slot & 7)) * 16;     // Phase B: 8 i-grps/XCD x 4 b-quarters
    const int b0B = (slot >> 3) * 8;

    const int jtA = pos & 1;
    const int btA = pos >> 1;
    const int ipB = pos & 3;
    const int bpB = pos >> 2;

    // out-row ownership: 4 writer blocks per XCD, one row each
    const int  lr     = slot & 15;
    const bool writer = ((slot & 7) == xcd) && (wv == (lr >> 1));
    const int  rrW    = lr & 1;

    // gamma/beta resident in LDS
    for (int i = tid; i < CC; i += NTHR) {
        smem[GB_G + i] = gamma[i];
        smem[GB_B + i] = beta[i];
    }

    // Bias hoist: load once, materialize now (keeps compiler waits out of
    // the counted-vmcnt pipeline regions).
    float ba_reg = (tid < 256) ? ba[j0 + (tid & 15)] : 0.f;
    float bb_reg = (tid < 128) ? bbv[i0 + (tid & 15)] : 0.f;
    asm volatile("" : "+v"(ba_reg), "+v"(bb_reg));

    int t;
    nfloat4 hz[8];
    float acc[32];
    float accB[16];

    // ---- stage helpers (uniform per-wave vmem counts for counted waits) ---
    auto issue_wa = [&](int c, int base) {   // 4 loads/wave (Wa col-chunk c)
        #pragma unroll
        for (int s = 0; s < 4; ++s) {
            const int q = wv * 4 + s;
            const int jr = q >> 1, hf = q & 1;
            async_cp16(Wa + (size_t)(j0 + jr) * CC2 + c * 512 + hf * 256 + lane * 4,
                       &smem[base + RWOFF + jr * 512 + (jr >= 8 ? 4 : 0) + hf * 256]);
        }
    };
    auto issue_x = [&](int c, int base) {    // 4 loads/wave (c in {2,3}: x cols)
        #pragma unroll
        for (int s = 0; s < 4; ++s) {
            const int q = wv * 4 + s;
            const int r = q >> 1, hf = q & 1;
            async_cp16(x + (size_t)(b0A + r) * TT * CC + (size_t)t * CC
                         + (c - 2) * 512 + hf * 256 + lane * 4,
                       &smem[base + r * 512 + ((r >> 2) << 2) + hf * 256]);
        }
    };
    auto dsw_z = [&](int c, int base) {      // h-chunk from registers (lgkm only)
        #pragma unroll
        for (int s = 0; s < 4; ++s) {
            const int r = wv * 2 + (s >> 1), hf = s & 1;
            *(nfloat4*)&smem[base + r * 512 + ((r >> 2) << 2) + hf * 256 + lane * 4]
                = hz[c * 4 + s];
        }
    };
    auto issue_y = [&](int c, int base) {    // 2 loads/wave (coherent)
        #pragma unroll
        for (int s = 0; s < 2; ++s) {
            const int q = wv * 2 + s;
            const int r = q >> 1, hf = q & 1;
            async_cp16_coh(y_ws + (size_t)(b0B + r) * CC2 + c * 512 + hf * 256 + lane * 4,
                           &smem[base + r * 512 + ((r >> 2) << 2) + hf * 256]);
        }
    };
    auto issue_wb = [&](int c, int base) {   // 4 loads/wave
        #pragma unroll
        for (int s = 0; s < 4; ++s) {
            const int q = wv * 4 + s;
            const int ir = q >> 1, hf = q & 1;
            async_cp16(Wb + (size_t)(i0 + ir) * CC2 + c * 512 + hf * 256 + lane * 4,
                       &smem[base + RWOFF + ir * 512 + ((ir >> 2) << 2) + hf * 256]);
        }
    };
    auto computeA = [&](int base) {
        const int zb = base, wb = base + RWOFF;
        const int k0 = (wv * 8 + ks) * 8;
        #pragma unroll
        for (int kk = 0; kk < 8; kk += 4) {
            const int k = k0 + kk;
            float4 zz[4];
            #pragma unroll
            for (int b2 = 0; b2 < 4; ++b2)
                zz[b2] = *(const float4*)&smem[zb + (btA * 4 + b2) * 512 + btA * 4 + k];
            #pragma unroll
            for (int jj = 0; jj < 8; ++jj) {
                const float4 ww = *(const float4*)&smem[wb + (jtA * 8 + jj) * 512 + jtA * 4 + k];
                #pragma unroll
                for (int b2 = 0; b2 < 4; ++b2) {
                    const float4 zv = zz[b2];
                    float& A = acc[jj * 4 + b2];
                    A = fmaf(ww.x, zv.x, fmaf(ww.y, zv.y, fmaf(ww.z, zv.z, fmaf(ww.w, zv.w, A))));
                }
            }
        }
    };
    auto computeB = [&](int base) {
        const int yb = base, wb = base + RWOFF;
        const int k0 = (wv * 8 + ks) * 8;
        #pragma unroll
        for (int kk = 0; kk < 8; kk += 4) {
            const int k = k0 + kk;
            float4 yy[4];
            #pragma unroll
            for (int b2 = 0; b2 < 4; ++b2)
                yy[b2] = *(const float4*)&smem[yb + (bpB * 4 + b2) * 512 + bpB * 4 + k];
            #pragma unroll
            for (int ii = 0; ii < 4; ++ii) {
                const float4 ww = *(const float4*)&smem[wb + (ipB * 4 + ii) * 512 + ipB * 4 + k];
                #pragma unroll
                for (int b2 = 0; b2 < 4; ++b2) {
                    const float4 yv = yy[b2];
                    float& A = accB[ii * 4 + b2];
                    A = fmaf(ww.x, yv.x, fmaf(ww.y, yv.y, fmaf(ww.z, yv.z, fmaf(ww.w, yv.w, A))));
                }
            }
        }
    };

    unsigned ph = 0;

    for (t = 0; t <= TT; ++t) {
        // ====== bar2 (top): wait y2[t-1]; x/Wa(x-cols) prefetch under it =====
        if (t > 0) {
            __threadfence_block();      // waitcnt: y2 coherent stores retired
            __syncthreads();            // block done with step t-1
            if (t < TT) {               // pure-input prefetch flies during bar
                issue_x(2, RB0); issue_x(3, RB1);
                issue_wa(2, RB0); issue_wa(3, RB1);
            }
            bar_core(cnt, ++ph, blk, tid);
            // ---- prologue: hz = LN(y2[t-1]) + y2[t-1] (h(t), registers) ----
            #pragma unroll
            for (int u = 0; u < 8; ++u) {
                const int c2 = u >> 2, rr = (u >> 1) & 1, hf = u & 1;
                hz[u] = coh_load_f32x4_nowait(
                    y2_ws + (size_t)(b0A + wv * 2 + rr) * CC + c2 * 512 + hf * 256 + lane * 4);
            }
            WAIT_VM(0);                 // hz + all prefetches landed (this wave)
            float s0 = 0.f, ss0 = 0.f, s1 = 0.f, ss1 = 0.f;
            #pragma unroll
            for (int u = 0; u < 8; ++u) {
                const int rr = (u >> 1) & 1;
                const float ls  = hz[u][0] + hz[u][1] + hz[u][2] + hz[u][3];
                const float lss = hz[u][0]*hz[u][0] + hz[u][1]*hz[u][1]
                                + hz[u][2]*hz[u][2] + hz[u][3]*hz[u][3];
                if (rr == 0) { s0 += ls; ss0 += lss; } else { s1 += ls; ss1 += lss; }
            }
            #pragma unroll
            for (int off = 1; off < 64; off <<= 1) {
                s0  += __shfl_xor(s0,  off);
                ss0 += __shfl_xor(ss0, off);
                s1  += __shfl_xor(s1,  off);
                ss1 += __shfl_xor(ss1, off);
            }
            const float mu0 = s0 * (1.0f / CC);
            const float mu1 = s1 * (1.0f / CC);
            const float rs0 = 1.0f / sqrtf(ss0 * (1.0f / CC) - mu0 * mu0 + LNEPS);
            const float rs1 = 1.0f / sqrtf(ss1 * (1.0f / CC) - mu1 * mu1 + LNEPS);
            #pragma unroll
            for (int u = 0; u < 8; ++u) {
                const int rr  = (u >> 1) & 1;
                const int col = (u >> 2) * 512 + (u & 1) * 256 + lane * 4;
                const nfloat4 g4 = *(const nfloat4*)&smem[GB_G + col];
                const nfloat4 b4 = *(const nfloat4*)&smem[GB_B + col];
                const float mu = rr ? mu1 : mu0;
                const float rs = rr ? rs1 : rs0;
                #pragma unroll
                for (int e = 0; e < 4; ++e)
                    hz[u][e] = (hz[u][e] - mu) * rs * g4[e] + b4[e] + hz[u][e];
            }
            if (writer) {   // out[b0A+lr][t-1][:] - 4 KB, 4 writer blocks/XCD
                #pragma unroll
                for (int c2 = 0; c2 < 2; ++c2)
                #pragma unroll
                for (int hf = 0; hf < 2; ++hf) {
                    const int u = c2 * 4 + rrW * 2 + hf;
                    __builtin_nontemporal_store(hz[u],
                        (nfloat4*)(out + ((size_t)(b0A + lr) * TT + (t - 1)) * CC
                                       + c2 * 512 + hf * 256 + lane * 4));
                }
            }
        } else {
            issue_x(2, RB0); issue_x(3, RB1);     // step-0 prefetch
            issue_wa(2, RB0); issue_wa(3, RB1);
            const nfloat4 z4 = {0.f, 0.f, 0.f, 0.f};
            #pragma unroll
            for (int u = 0; u < 8; ++u) hz[u] = z4; // h0 = 0 exactly
            WAIT_VM(0);
        }
        if (t == TT) break;   // final iteration only emits out[1023]

        // ====== Phase A: y = gelu([h||x] @ Wa^T + ba), x-chunks FIRST ========
        // c0/c1 = x-cols (prefetched under bar2, zero stall); c2/c3 = h-cols
        // (ds_write from regs; their Wa cols stage under c0/c1 compute).
        #pragma unroll
        for (int a = 0; a < 32; ++a) acc[a] = 0.f;

        SBAR();                                    // all waves' prefetch landed
        computeA(RB0);                             // x-chunk 0 (K 1024..1535)
        SBAR();
        dsw_z(0, RB0); issue_wa(0, RB0);
        computeA(RB1);                             // x-chunk 1 (K 1536..2047)
        SBAR();
        dsw_z(1, RB1); issue_wa(1, RB1);
        WAIT_VM(4); WAIT_LGKM0; SBAR();
        computeA(RB0);                             // h-chunk 0 (K 0..511)
        WAIT_VM(0); SBAR();
        computeA(RB1);                             // h-chunk 1 (K 512..1023)

        #pragma unroll
        for (int a = 0; a < 32; ++a) {
            float v = acc[a];
            v += __shfl_xor(v, 8);
            v += __shfl_xor(v, 16);
            v += __shfl_xor(v, 32);
            acc[a] = v;
        }
        if (lane < 8) {
            #pragma unroll
            for (int a4 = 0; a4 < 32; a4 += 4)
                *(float4*)&smem[SC0F + wv * 288 + lane * 36 + a4] =
                    make_float4(acc[a4], acc[a4 + 1], acc[a4 + 2], acc[a4 + 3]);
        }
        WAIT_LGKM0; SBAR();
        if (tid < 256) {
            const int bl = tid >> 4, jl = tid & 15;
            const int p2 = (bl >> 2) * 2 + (jl >> 3);
            const int a2 = (jl & 7) * 4 + (bl & 3);
            float s = ba_reg;
            #pragma unroll
            for (int w2 = 0; w2 < 8; ++w2) s += smem[SC0F + w2 * 288 + p2 * 36 + a2];
            coh_store(&y_ws[(size_t)(b0A + bl) * CC2 + j0 + jl], gelu_exact(s));
        }

        // ====== bar1: wait y; Wb prefetch under it ===========================
        __threadfence_block();
        __syncthreads();
        issue_wb(0, RB0); issue_wb(1, RB1);
        bar_core(cnt, ++ph, blk, tid);

        // ====== Phase B pipeline: y2 = y @ Wb^T + bb =========================
        #pragma unroll
        for (int a = 0; a < 16; ++a) accB[a] = 0.f;

        issue_y(0, RB0); issue_y(1, RB1);
        WAIT_VM(2); SBAR();
        computeB(RB0);                             // c0 (y0 + wb0)
        SBAR();
        issue_wb(2, RB0); issue_y(2, RB0);
        WAIT_VM(6); SBAR();
        computeB(RB1);                             // c1 (y1 + wb1)
        SBAR();
        issue_wb(3, RB1); issue_y(3, RB1);
        WAIT_VM(6); SBAR();
        computeB(RB0);                             // c2 (y2 + wb2)
        WAIT_VM(0); SBAR();
        computeB(RB1);                             // c3 (y3 + wb3)

        #pragma unroll
        for (int a = 0; a < 16; ++a) {
            float v = accB[a];
            v += __shfl_xor(v, 8);
            v += __shfl_xor(v, 16);
            v += __shfl_xor(v, 32);
            accB[a] = v;
        }
        if (lane < 8) {
            #pragma unroll
            for (int a4 = 0; a4 < 16; a4 += 4)
                *(float4*)&smem[SC0F + wv * 160 + lane * 20 + a4] =
                    make_float4(accB[a4], accB[a4 + 1], accB[a4 + 2], accB[a4 + 3]);
        }
        WAIT_LGKM0; SBAR();
        if (tid < 128) {
            const int bl = tid >> 4, il = tid & 15;
            const int p2 = (bl >> 2) * 4 + (il >> 2);
            const int a2 = (il & 3) * 4 + (bl & 3);
            float s = bb_reg;
            #pragma unroll
            for (int w2 = 0; w2 < 8; ++w2) s += smem[SC0F + w2 * 160 + p2 * 20 + a2];
            coh_store(&y2_ws[(size_t)(b0B + bl) * CC + i0 + il], s);
        }
        // bar2 happens at the top of the next iteration (prefetch under it)
    }
}

extern "C" void kernel_launch(void* const* d_in, const int* in_sizes, int n_in,
                              void* d_out, int out_size, void* d_ws, size_t ws_size,
                              hipStream_t stream) {
    const float* x     = (const float*)d_in[0];
    const float* Wa    = (const float*)d_in[1];
    const float* ba    = (const float*)d_in[2];
    const float* Wb    = (const float*)d_in[3];
    const float* bb    = (const float*)d_in[4];
    const float* gamma = (const float*)d_in[5];
    const float* beta  = (const float*)d_in[6];
    float* out = (float*)d_out;
    float* ws  = (float*)d_ws;

    hipLaunchKernelGGL(rpe_init, dim3(1), dim3(512), 0, stream, ws);
    hipLaunchKernelGGL(rpe_main, dim3(NBLK), dim3(NTHR), 0, stream,
                       x, Wa, ba, Wb, bb, gamma, beta, out, ws);
}

// Round 5
// 28772.961 us; speedup vs baseline: 1.4979x; 1.4979x over previous
//
#include <hip/hip_runtime.h>
#include <math.h>

// Problem constants: B=32, T=1024, C=1024
#define CC    1024
#define CC2   2048
#define BB    32
#define TT    1024
#define NBLK  256      // persistent grid: 1 block/CU, all co-resident
#define NTHR  512      // 8 waves/block
#define LNEPS 1e-5f

// Workspace layout (float indices)
#define WS_Y    32768    // y:  32*2048 (coherent: sc-bypass stores/loads only)
#define WS_Y2   98304    // y2: 32*1024 (coherent)
#define WS_BARF 131072   // barrier region: 768 u32 (cnt[64]@str8 + rep[32]@str8)

// LDS layout (float offsets). Two 16448-float pipeline buffers, each split
// into an activation region (z for A / y for B) and a weight region (Wa/Wb).
#define RB0   0
#define RB1   16448
#define RWOFF 8224
#define SC0F  32896      // reduce scratch (2304 floats)
#define GB_G  35200      // gamma[1024]
#define GB_B  36224      // beta[1024]
#define SMEMN 37248      // 148,992 B (< 160 KiB/CU)

// CPol aux bits (gfx950): bit0=SC0, bit4=SC1. SC0|SC1 = system coherent point.
#define AUX_CACHED 0
#define AUX_COH    17

// Barrier geometry: 32B stride keeps per-cacheline poller/atomic counts tiny.
#define CSTR    8        // u32 stride between barrier words (32 B)
#define REP_OFF 512      // u32 offset of release replicas

typedef float    nfloat4 __attribute__((ext_vector_type(4)));
typedef unsigned nuint4  __attribute__((ext_vector_type(4)));

// Counted waits + raw barriers: avoids __syncthreads()'s vmcnt(0) drain so
// prefetched global_load_lds stay in flight across barriers (T3/T4 pattern).
#define WAIT_VM(N)  do { asm volatile("s_waitcnt vmcnt(" #N ")" ::: "memory"); \
                         __builtin_amdgcn_sched_barrier(0); } while (0)
#define WAIT_LGKM0  do { asm volatile("s_waitcnt lgkmcnt(0)" ::: "memory"); \
                         __builtin_amdgcn_sched_barrier(0); } while (0)
#define SBAR()      do { __builtin_amdgcn_s_barrier(); \
                         __builtin_amdgcn_sched_barrier(0); } while (0)

__global__ void rpe_init(float* __restrict__ ws) {
    unsigned* bar = (unsigned*)(ws + WS_BARF);
    const int i = blockIdx.x * blockDim.x + threadIdx.x;
    if (i < 1024) bar[i] = 0u;   // cnt + rep (+pad); ws poisoned 0xAA
}

// ---- coherent primitives --------------------------------------------------
__device__ __forceinline__ unsigned spin_load_u32(const unsigned* p) {
    unsigned v;
    asm volatile("global_load_dword %0, %1, off sc0 sc1\n\ts_waitcnt vmcnt(0)"
                 : "=&v"(v) : "v"(p) : "memory");
    return v;
}
__device__ __forceinline__ nfloat4 coh_load_f32x4_nowait(const float* p) {
    nfloat4 v;
    asm volatile("global_load_dwordx4 %0, %1, off sc0 sc1"
                 : "=&v"(v) : "v"(p));
    return v;
}
__device__ __forceinline__ void async_cp16(const float* g, float* l) {
    __builtin_amdgcn_global_load_lds(
        (const __attribute__((address_space(1))) void*)g,
        (__attribute__((address_space(3))) void*)l, 16, 0, AUX_CACHED);
}
__device__ __forceinline__ void async_cp16_coh(const float* g, float* l) {
    __builtin_amdgcn_global_load_lds(
        (const __attribute__((address_space(1))) void*)g,
        (__attribute__((address_space(3))) void*)l, 16, 0, AUX_COH);
}
__device__ __forceinline__ void coh_store(float* p, float v) {
    __hip_atomic_store(p, v, __ATOMIC_RELAXED, __HIP_MEMORY_SCOPE_AGENT);
}
__device__ __forceinline__ void coh_store_u32(unsigned* p, unsigned v) {
    __hip_atomic_store(p, v, __ATOMIC_RELAXED, __HIP_MEMORY_SCOPE_AGENT);
}
__device__ __forceinline__ float gelu_exact(float a) {
    return 0.5f * a * (1.0f + erff(a * 0.70710678118654752440f));
}

// ---- grid barrier: low-contention arrive / detect / replicated release ----
// Round-3 pathology: 255 pollers + /8 RMW fallback on ONE gen line (RMWs
// serialize at the LLC atomic unit). Round-4 pathology: 256 blocks x 64
// lanes polling 4 cachelines (read flood starves the arrival atomics).
// This design bounds every line's traffic:
//   arrive:  atomicAdd on 64 counters (32B stride) -> <=8 atomics/line
//   detect:  block 0 wave 0 only, 1 word/lane      -> <=2 pollers/line
//   release: 32 replicas (32B stride), 1 lane/block polls its own replica
//            -> <=16 load-only pollers/line; RMW valve /1024 (hang-safety)
__device__ __forceinline__ void bar_core(unsigned* bar, unsigned phase,
                                         int blk, int tid) {
    unsigned* cnt = bar;
    unsigned* rep = bar + REP_OFF;
    if (tid == 0)
        __hip_atomic_fetch_add(&cnt[(blk & 63) * CSTR], 1u,
                               __ATOMIC_RELAXED, __HIP_MEMORY_SCOPE_AGENT);
    if (blk == 0) {
        if (tid < 64) {
            const unsigned target = 4u * phase;   // 4 blocks per counter
            unsigned* w = cnt + tid * CSTR;
            int n = 0;
            for (;;) {
                unsigned v = ((++n & 1023) == 0)
                    ? __hip_atomic_fetch_add(w, 0u, __ATOMIC_RELAXED,
                                             __HIP_MEMORY_SCOPE_AGENT)
                    : spin_load_u32(w);
                if (__ballot(v >= target) == ~0ull) break;
                __builtin_amdgcn_s_sleep(2);
            }
            if (tid < 32) coh_store_u32(&rep[tid * CSTR], phase);  // broadcast
        }
    } else if (tid == 0) {
        unsigned* w = rep + (blk & 31) * CSTR;
        int n = 0;
        for (;;) {
            unsigned v = ((++n & 1023) == 0)
                ? __hip_atomic_fetch_add(w, 0u, __ATOMIC_RELAXED,
                                         __HIP_MEMORY_SCOPE_AGENT)
                : spin_load_u32(w);
            if (v >= phase) break;
            __builtin_amdgcn_s_sleep(2);
        }
    }
    SBAR();   // raw barrier: do NOT drain vmcnt (prefetches stay in flight)
}

extern "C" __global__ void __launch_bounds__(NTHR)
rpe_main(const float* __restrict__ x,  const float* __restrict__ Wa,
         const float* __restrict__ ba, const float* __restrict__ Wb,
         const float* __restrict__ bbv, const float* __restrict__ gamma,
         const float* __restrict__ beta, float* __restrict__ out,
         float* __restrict__ ws)
{
    float*    y_ws  = ws + WS_Y;
    float*    y2_ws = ws + WS_Y2;
    unsigned* bar   = (unsigned*)(ws + WS_BARF);

    const int tid  = threadIdx.x;
    const int blk  = blockIdx.x;
    const int wv   = tid >> 6;
    const int lane = tid & 63;
    const int pos  = lane & 7;
    const int ks   = lane >> 3;

    __shared__ float smem[SMEMN];

    // XCD-partner mapping (perf-only): blocks sharing a weight slice land on
    // the same XCD (blk%8 round-robin) -> per-XCD Wa 2MB + Wb 1MB < 4MB L2.
    const int xcd  = blk & 7;
    const int slot = blk >> 3;

    const int j0  = (xcd * 16 + (slot & 15)) * 16;   // Phase A: 16 j-grps/XCD x 2 b-halves
    const int b0A = (slot >> 4) * 16;
    const int i0  = (xcd * 8 + (slot & 7)) * 16;     // Phase B: 8 i-grps/XCD x 4 b-quarters
    const int b0B = (slot >> 3) * 8;

    const int jtA = pos & 1;
    const int btA = pos >> 1;
    const int ipB = pos & 3;
    const int bpB = pos >> 2;

    // out-row ownership: 4 writer blocks per XCD, one row each
    const int  lr     = slot & 15;
    const bool writer = ((slot & 7) == xcd) && (wv == (lr >> 1));
    const int  rrW    = lr & 1;

    // gamma/beta resident in LDS
    for (int i = tid; i < CC; i += NTHR) {
        smem[GB_G + i] = gamma[i];
        smem[GB_B + i] = beta[i];
    }

    // Bias hoist: load once, materialize now (keeps compiler waits out of
    // the counted-vmcnt pipeline regions).
    float ba_reg = (tid < 256) ? ba[j0 + (tid & 15)] : 0.f;
    float bb_reg = (tid < 128) ? bbv[i0 + (tid & 15)] : 0.f;
    asm volatile("" : "+v"(ba_reg), "+v"(bb_reg));

    int t;
    nfloat4 hz[8];
    float acc[32];
    float accB[16];

    // ---- stage helpers (uniform per-wave vmem counts for counted waits) ---
    auto issue_wa = [&](int c, int base) {   // 4 loads/wave (Wa col-chunk c)
        #pragma unroll
        for (int s = 0; s < 4; ++s) {
            const int q = wv * 4 + s;
            const int jr = q >> 1, hf = q & 1;
            async_cp16(Wa + (size_t)(j0 + jr) * CC2 + c * 512 + hf * 256 + lane * 4,
                       &smem[base + RWOFF + jr * 512 + (jr >= 8 ? 4 : 0) + hf * 256]);
        }
    };
    auto issue_x = [&](int c, int base) {    // 4 loads/wave (c in {2,3}: x cols)
        #pragma unroll
        for (int s = 0; s < 4; ++s) {
            const int q = wv * 4 + s;
            const int r = q >> 1, hf = q & 1;
            async_cp16(x + (size_t)(b0A + r) * TT * CC + (size_t)t * CC
                         + (c - 2) * 512 + hf * 256 + lane * 4,
                       &smem[base + r * 512 + ((r >> 2) << 2) + hf * 256]);
        }
    };
    auto dsw_z = [&](int c, int base) {      // h-chunk from registers (lgkm only)
        #pragma unroll
        for (int s = 0; s < 4; ++s) {
            const int r = wv * 2 + (s >> 1), hf = s & 1;
            *(nfloat4*)&smem[base + r * 512 + ((r >> 2) << 2) + hf * 256 + lane * 4]
                = hz[c * 4 + s];
        }
    };
    auto issue_y = [&](int c, int base) {    // 2 loads/wave (coherent)
        #pragma unroll
        for (int s = 0; s < 2; ++s) {
            const int q = wv * 2 + s;
            const int r = q >> 1, hf = q & 1;
            async_cp16_coh(y_ws + (size_t)(b0B + r) * CC2 + c * 512 + hf * 256 + lane * 4,
                           &smem[base + r * 512 + ((r >> 2) << 2) + hf * 256]);
        }
    };
    auto issue_wb = [&](int c, int base) {   // 4 loads/wave
        #pragma unroll
        for (int s = 0; s < 4; ++s) {
            const int q = wv * 4 + s;
            const int ir = q >> 1, hf = q & 1;
            async_cp16(Wb + (size_t)(i0 + ir) * CC2 + c * 512 + hf * 256 + lane * 4,
                       &smem[base + RWOFF + ir * 512 + ((ir >> 2) << 2) + hf * 256]);
        }
    };
    auto computeA = [&](int base) {
        const int zb = base, wb = base + RWOFF;
        const int k0 = (wv * 8 + ks) * 8;
        #pragma unroll
        for (int kk = 0; kk < 8; kk += 4) {
            const int k = k0 + kk;
            float4 zz[4];
            #pragma unroll
            for (int b2 = 0; b2 < 4; ++b2)
                zz[b2] = *(const float4*)&smem[zb + (btA * 4 + b2) * 512 + btA * 4 + k];
            #pragma unroll
            for (int jj = 0; jj < 8; ++jj) {
                const float4 ww = *(const float4*)&smem[wb + (jtA * 8 + jj) * 512 + jtA * 4 + k];
                #pragma unroll
                for (int b2 = 0; b2 < 4; ++b2) {
                    const float4 zv = zz[b2];
                    float& A = acc[jj * 4 + b2];
                    A = fmaf(ww.x, zv.x, fmaf(ww.y, zv.y, fmaf(ww.z, zv.z, fmaf(ww.w, zv.w, A))));
                }
            }
        }
    };
    auto computeB = [&](int base) {
        const int yb = base, wb = base + RWOFF;
        const int k0 = (wv * 8 + ks) * 8;
        #pragma unroll
        for (int kk = 0; kk < 8; kk += 4) {
            const int k = k0 + kk;
            float4 yy[4];
            #pragma unroll
            for (int b2 = 0; b2 < 4; ++b2)
                yy[b2] = *(const float4*)&smem[yb + (bpB * 4 + b2) * 512 + bpB * 4 + k];
            #pragma unroll
            for (int ii = 0; ii < 4; ++ii) {
                const float4 ww = *(const float4*)&smem[wb + (ipB * 4 + ii) * 512 + ipB * 4 + k];
                #pragma unroll
                for (int b2 = 0; b2 < 4; ++b2) {
                    const float4 yv = yy[b2];
                    float& A = accB[ii * 4 + b2];
                    A = fmaf(ww.x, yv.x, fmaf(ww.y, yv.y, fmaf(ww.z, yv.z, fmaf(ww.w, yv.w, A))));
                }
            }
        }
    };

    unsigned ph = 0;

    for (t = 0; t <= TT; ++t) {
        // ====== bar2 (top): wait y2[t-1]; x/Wa(x-cols) prefetch under it =====
        if (t > 0) {
            __threadfence_block();      // waitcnt: y2 coherent stores retired
            __syncthreads();            // block done with step t-1
            if (t < TT) {               // pure-input prefetch flies during bar
                issue_x(2, RB0); issue_x(3, RB1);
                issue_wa(2, RB0); issue_wa(3, RB1);
            }
            bar_core(bar, ++ph, blk, tid);
            // ---- prologue: hz = LN(y2[t-1]) + y2[t-1] (h(t), registers) ----
            #pragma unroll
            for (int u = 0; u < 8; ++u) {
                const int c2 = u >> 2, rr = (u >> 1) & 1, hf = u & 1;
                hz[u] = coh_load_f32x4_nowait(
                    y2_ws + (size_t)(b0A + wv * 2 + rr) * CC + c2 * 512 + hf * 256 + lane * 4);
            }
            WAIT_VM(0);                 // hz + all prefetches landed (this wave)
            float s0 = 0.f, ss0 = 0.f, s1 = 0.f, ss1 = 0.f;
            #pragma unroll
            for (int u = 0; u < 8; ++u) {
                const int rr = (u >> 1) & 1;
                const float ls  = hz[u][0] + hz[u][1] + hz[u][2] + hz[u][3];
                const float lss = hz[u][0]*hz[u][0] + hz[u][1]*hz[u][1]
                                + hz[u][2]*hz[u][2] + hz[u][3]*hz[u][3];
                if (rr == 0) { s0 += ls; ss0 += lss; } else { s1 += ls; ss1 += lss; }
            }
            #pragma unroll
            for (int off = 1; off < 64; off <<= 1) {
                s0  += __shfl_xor(s0,  off);
                ss0 += __shfl_xor(ss0, off);
                s1  += __shfl_xor(s1,  off);
                ss1 += __shfl_xor(ss1, off);
            }
            const float mu0 = s0 * (1.0f / CC);
            const float mu1 = s1 * (1.0f / CC);
            const float rs0 = 1.0f / sqrtf(ss0 * (1.0f / CC) - mu0 * mu0 + LNEPS);
            const float rs1 = 1.0f / sqrtf(ss1 * (1.0f / CC) - mu1 * mu1 + LNEPS);
            #pragma unroll
            for (int u = 0; u < 8; ++u) {
                const int rr  = (u >> 1) & 1;
                const int col = (u >> 2) * 512 + (u & 1) * 256 + lane * 4;
                const nfloat4 g4 = *(const nfloat4*)&smem[GB_G + col];
                const nfloat4 b4 = *(const nfloat4*)&smem[GB_B + col];
                const float mu = rr ? mu1 : mu0;
                const float rs = rr ? rs1 : rs0;
                #pragma unroll
                for (int e = 0; e < 4; ++e)
                    hz[u][e] = (hz[u][e] - mu) * rs * g4[e] + b4[e] + hz[u][e];
            }
            if (writer) {   // out[b0A+lr][t-1][:] - 4 KB, 4 writer blocks/XCD
                #pragma unroll
                for (int c2 = 0; c2 < 2; ++c2)
                #pragma unroll
                for (int hf = 0; hf < 2; ++hf) {
                    const int u = c2 * 4 + rrW * 2 + hf;
                    __builtin_nontemporal_store(hz[u],
                        (nfloat4*)(out + ((size_t)(b0A + lr) * TT + (t - 1)) * CC
                                       + c2 * 512 + hf * 256 + lane * 4));
                }
            }
        } else {
            issue_x(2, RB0); issue_x(3, RB1);     // step-0 prefetch
            issue_wa(2, RB0); issue_wa(3, RB1);
            const nfloat4 z4 = {0.f, 0.f, 0.f, 0.f};
            #pragma unroll
            for (int u = 0; u < 8; ++u) hz[u] = z4; // h0 = 0 exactly
            WAIT_VM(0);
        }
        if (t == TT) break;   // final iteration only emits out[1023]

        // ====== Phase A: y = gelu([h||x] @ Wa^T + ba), x-chunks FIRST ========
        // c0/c1 = x-cols (prefetched under bar2, zero stall); c2/c3 = h-cols
        // (ds_write from regs; their Wa cols stage under c0/c1 compute).
        #pragma unroll
        for (int a = 0; a < 32; ++a) acc[a] = 0.f;

        SBAR();                                    // all waves' prefetch landed
        computeA(RB0);                             // x-chunk 0 (K 1024..1535)
        SBAR();
        dsw_z(0, RB0); issue_wa(0, RB0);
        computeA(RB1);                             // x-chunk 1 (K 1536..2047)
        SBAR();
        dsw_z(1, RB1); issue_wa(1, RB1);
        WAIT_VM(4); WAIT_LGKM0; SBAR();
        computeA(RB0);                             // h-chunk 0 (K 0..511)
        WAIT_VM(0); SBAR();
        computeA(RB1);                             // h-chunk 1 (K 512..1023)

        #pragma unroll
        for (int a = 0; a < 32; ++a) {
            float v = acc[a];
            v += __shfl_xor(v, 8);
            v += __shfl_xor(v, 16);
            v += __shfl_xor(v, 32);
            acc[a] = v;
        }
        if (lane < 8) {
            #pragma unroll
            for (int a4 = 0; a4 < 32; a4 += 4)
                *(float4*)&smem[SC0F + wv * 288 + lane * 36 + a4] =
                    make_float4(acc[a4], acc[a4 + 1], acc[a4 + 2], acc[a4 + 3]);
        }
        WAIT_LGKM0; SBAR();
        if (tid < 256) {
            const int bl = tid >> 4, jl = tid & 15;
            const int p2 = (bl >> 2) * 2 + (jl >> 3);
            const int a2 = (jl & 7) * 4 + (bl & 3);
            float s = ba_reg;
            #pragma unroll
            for (int w2 = 0; w2 < 8; ++w2) s += smem[SC0F + w2 * 288 + p2 * 36 + a2];
            coh_store(&y_ws[(size_t)(b0A + bl) * CC2 + j0 + jl], gelu_exact(s));
        }

        // ====== bar1: wait y; Wb prefetch under it ===========================
        __threadfence_block();
        __syncthreads();
        issue_wb(0, RB0); issue_wb(1, RB1);
        bar_core(bar, ++ph, blk, tid);

        // ====== Phase B pipeline: y2 = y @ Wb^T + bb =========================
        #pragma unroll
        for (int a = 0; a < 16; ++a) accB[a] = 0.f;

        issue_y(0, RB0); issue_y(1, RB1);
        WAIT_VM(2); SBAR();
        computeB(RB0);                             // c0 (y0 + wb0)
        SBAR();
        issue_wb(2, RB0); issue_y(2, RB0);
        WAIT_VM(6); SBAR();
        computeB(RB1);                             // c1 (y1 + wb1)
        SBAR();
        issue_wb(3, RB1); issue_y(3, RB1);
        WAIT_VM(6); SBAR();
        computeB(RB0);                             // c2 (y2 + wb2)
        WAIT_VM(0); SBAR();
        computeB(RB1);                             // c3 (y3 + wb3)

        #pragma unroll
        for (int a = 0; a < 16; ++a) {
            float v = accB[a];
            v += __shfl_xor(v, 8);
            v += __shfl_xor(v, 16);
            v += __shfl_xor(v, 32);
            accB[a] = v;
        }
        if (lane < 8) {
            #pragma unroll
            for (int a4 = 0; a4 < 16; a4 += 4)
                *(float4*)&smem[SC0F + wv * 160 + lane * 20 + a4] =
                    make_float4(accB[a4], accB[a4 + 1], accB[a4 + 2], accB[a4 + 3]);
        }
        WAIT_LGKM0; SBAR();
        if (tid < 128) {
            const int bl = tid >> 4, il = tid & 15;
            const int p2 = (bl >> 2) * 4 + (il >> 2);
            const int a2 = (il & 3) * 4 + (bl & 3);
            float s = bb_reg;
            #pragma unroll
            for (int w2 = 0; w2 < 8; ++w2) s += smem[SC0F + w2 * 160 + p2 * 20 + a2];
            coh_store(&y2_ws[(size_t)(b0B + bl) * CC + i0 + il], s);
        }
        // bar2 happens at the top of the next iteration (prefetch under it)
    }
}

extern "C" void kernel_launch(void* const* d_in, const int* in_sizes, int n_in,
                              void* d_out, int out_size, void* d_ws, size_t ws_size,
                              hipStream_t stream) {
    const float* x     = (const float*)d_in[0];
    const float* Wa    = (const float*)d_in[1];
    const float* ba    = (const float*)d_in[2];
    const float* Wb    = (const float*)d_in[3];
    const float* bb    = (const float*)d_in[4];
    const float* gamma = (const float*)d_in[5];
    const float* beta  = (const float*)d_in[6];
    float* out = (float*)d_out;
    float* ws  = (float*)d_ws;

    hipLaunchKernelGGL(rpe_init, dim3(2), dim3(512), 0, stream, ws);
    hipLaunchKernelGGL(rpe_main, dim3(NBLK), dim3(NTHR), 0, stream,
                       x, Wa, ba, Wb, bb, gamma, beta, out, ws);
}